// Round 8
// baseline (257.936 us; speedup 1.0000x reference)
//
#include <hip/hip_runtime.h>

#define IN_CH 128
#define HID 64
#define OUT_CH 32
#define BUCKET_CAP 6144   // mean 4096, sigma ~64 for this E/N; overflow-guarded
#define NB_MAX 512

typedef _Float16 f16x8 __attribute__((ext_vector_type(8)));
typedef float f32x4 __attribute__((ext_vector_type(4)));

// ---------------------------------------------------------------------------
// bf16 helpers (RNE)
// ---------------------------------------------------------------------------
__device__ __forceinline__ unsigned short f32_to_bf16(float f) {
    union { float f; unsigned int u; } v; v.f = f;
    unsigned int u = v.u;
    u += 0x7FFFu + ((u >> 16) & 1u);
    return (unsigned short)(u >> 16);
}
__device__ __forceinline__ float bf16_to_f32(unsigned short h) {
    union { unsigned int u; float f; } v; v.u = ((unsigned int)h) << 16;
    return v.f;
}
__device__ __forceinline__ float bf16_lo(unsigned int u) {
    union { unsigned int u; float f; } v; v.u = u << 16; return v.f;
}
__device__ __forceinline__ float bf16_hi(unsigned int u) {
    union { unsigned int u; float f; } v; v.u = u & 0xFFFF0000u; return v.f;
}

// ---------------------------------------------------------------------------
// edge_index: int64 in reference; int32 possible from harness.
// ---------------------------------------------------------------------------
__device__ __forceinline__ int load_idx(const void* e, long long i, int is64) {
    if (is64) return ((const int*)e)[2 * i];  // little-endian low word
    return ((const int*)e)[i];
}

// ---------------------------------------------------------------------------
// binA: LDS-binned bucketing of edges by dst>>8 into fixed-capacity buckets.
// entry = (src << 8) | (dst & 255). int64-vs-int32 detection fused here.
// ---------------------------------------------------------------------------
__global__ __launch_bounds__(256) void binA_kernel(
    const void* __restrict__ edges, long long E,
    int* __restrict__ bucket_cur, unsigned int* __restrict__ entries, int nb) {
    __shared__ int hist[NB_MAX];
    __shared__ int cbase[NB_MAX];
    __shared__ int s_is64;
    const int tid = threadIdx.x;

    if (tid < 64) {
        int v = ((const int*)edges)[2 * tid + 1];
        unsigned long long nz = __ballot(v != 0);
        if (tid == 0) s_is64 = (nz == 0ull) ? 1 : 0;
    }
    for (int i = tid; i < nb; i += 256) hist[i] = 0;
    __syncthreads();
    const int is64 = s_is64;

    const long long per = (E + gridDim.x - 1) / gridDim.x;
    const long long lo = blockIdx.x * per;
    const long long hi = (lo + per < E) ? lo + per : E;

    for (long long i = lo + tid; i < hi; i += 256) {
        int dst = load_idx(edges, E + i, is64);
        atomicAdd(&hist[dst >> 8], 1);
    }
    __syncthreads();
    for (int i = tid; i < nb; i += 256) {
        int c = hist[i];
        int base = (c > 0) ? atomicAdd(&bucket_cur[i], c) : 0;
        cbase[i] = base;
        hist[i] = 0;  // reuse as running local offset
    }
    __syncthreads();
    for (long long i = lo + tid; i < hi; i += 256) {
        int src = load_idx(edges, i, is64);
        int dst = load_idx(edges, E + i, is64);
        int b = dst >> 8;
        int rel = cbase[b] + atomicAdd(&hist[b], 1);
        if (rel < BUCKET_CAP)
            entries[(long long)b * BUCKET_CAP + rel] = ((unsigned)src << 8) | (unsigned)(dst & 255);
    }
}

// ---------------------------------------------------------------------------
// binB1: block per bucket: LDS per-node hist + scan -> counts, row_off, dinv.
// ---------------------------------------------------------------------------
__global__ __launch_bounds__(256) void binB1_kernel(
    const unsigned int* __restrict__ entries, const int* __restrict__ bucket_cur,
    int* __restrict__ counts, int* __restrict__ row_off, float* __restrict__ dinv,
    int n) {
    __shared__ int hist[256];
    __shared__ int scan[256];
    const int b   = blockIdx.x;
    const int tid = threadIdx.x;
    const long long seg = (long long)b * BUCKET_CAP;
    int cnt = bucket_cur[b];
    if (cnt > BUCKET_CAP) cnt = BUCKET_CAP;

    hist[tid] = 0;
    __syncthreads();
    for (int i = tid; i < cnt; i += 256)
        atomicAdd(&hist[entries[seg + i] & 255], 1);
    __syncthreads();

    int v = hist[tid];
    scan[tid] = v;
    __syncthreads();
    for (int off = 1; off < 256; off <<= 1) {
        int t = (tid >= off) ? scan[tid - off] : 0;
        __syncthreads();
        scan[tid] += t;
        __syncthreads();
    }
    int ex = scan[tid] - v;
    int node = (b << 8) + tid;
    if (node < n) {
        counts[node]  = v;
        row_off[node] = (int)seg + ex;
        dinv[node]    = rsqrtf((float)v + 1.0f);  // +1 self-loop
    }
}

// ---------------------------------------------------------------------------
// binB2: block per bucket: node-sort entries into ew[] with the per-edge
// weight w = dinv[src]*dinv[dst] precomputed. ew entry = int2{src, bits(w)}.
// ---------------------------------------------------------------------------
__global__ __launch_bounds__(256) void binB2_kernel(
    const unsigned int* __restrict__ entries, const int* __restrict__ bucket_cur,
    const int* __restrict__ row_off, const float* __restrict__ dinv,
    int2* __restrict__ ew, int n) {
    __shared__ int cur[256];
    __shared__ float ldi[256];
    const int b   = blockIdx.x;
    const int tid = threadIdx.x;
    const long long seg = (long long)b * BUCKET_CAP;
    int cnt = bucket_cur[b];
    if (cnt > BUCKET_CAP) cnt = BUCKET_CAP;

    int node = (b << 8) + tid;
    cur[tid] = (node < n) ? row_off[node] - (int)seg : 0;
    ldi[tid] = (node < n) ? dinv[node] : 0.f;
    __syncthreads();

    for (int i = tid; i < cnt; i += 256) {
        unsigned e = entries[seg + i];
        int d = (int)(e & 255u);
        int s = (int)(e >> 8);
        int r = atomicAdd(&cur[d], 1);
        float w = dinv[s] * ldi[d];
        int2 o; o.x = s; o.y = __float_as_int(w);
        ew[seg + r] = o;
    }
}

// ---------------------------------------------------------------------------
// GEMM1 via MFMA f16 (round-4 proven version): m1 = x @ W1, fp32 accumulate,
// bf16 out. One wave = one 16-row x 64-col tile: 16 mfma. ZERO LDS/barriers.
// ---------------------------------------------------------------------------
__global__ __launch_bounds__(256) void gemm1_kernel(
    const float* __restrict__ x, const float* __restrict__ W1,
    unsigned short* __restrict__ m1bf, int n) {
    const int lane = threadIdx.x & 63;
    const int wid  = threadIdx.x >> 6;
    const int m    = lane & 15;   // A-row / B-col / D-col within tile
    const int g    = lane >> 4;   // k-group (and D row-group)
    const int Rw   = blockIdx.x * 64 + wid * 16;

    // B fragments: wf[c][t][j] = W1[t*32 + g*8 + j][c*16 + m]
    f16x8 wf[4][4];
#pragma unroll
    for (int t = 0; t < 4; ++t) {
        const float* wp = W1 + (t * 32 + g * 8) * HID + m;
#pragma unroll
        for (int c = 0; c < 4; ++c) {
#pragma unroll
            for (int j = 0; j < 8; ++j)
                wf[c][t][j] = (_Float16)wp[j * HID + c * 16];
        }
    }

    int rl = Rw + m;
    if (rl >= n) rl = n - 1;   // clamp loads; stores guarded below
    const float* xr = x + (long long)rl * IN_CH;

    f32x4 acc[4] = {};

#pragma unroll
    for (int t = 0; t < 4; ++t) {
        float4 xa = *(const float4*)(xr + t * 32 + g * 8);
        float4 xb = *(const float4*)(xr + t * 32 + g * 8 + 4);
        f16x8 af;
        af[0] = (_Float16)xa.x; af[1] = (_Float16)xa.y;
        af[2] = (_Float16)xa.z; af[3] = (_Float16)xa.w;
        af[4] = (_Float16)xb.x; af[5] = (_Float16)xb.y;
        af[6] = (_Float16)xb.z; af[7] = (_Float16)xb.w;
#pragma unroll
        for (int c = 0; c < 4; ++c)
            acc[c] = __builtin_amdgcn_mfma_f32_16x16x32_f16(af, wf[c][t], acc[c], 0, 0, 0);
    }

#pragma unroll
    for (int c = 0; c < 4; ++c) {
#pragma unroll
        for (int r = 0; r < 4; ++r) {
            int row = Rw + g * 4 + r;
            if (row < n)
                m1bf[(long long)row * HID + c * 16 + m] = f32_to_bf16(acc[c][r]);
        }
    }
}

// ---------------------------------------------------------------------------
// GEMM2 (register-tiled): m2 = h @ W2 (N x 64 @ 64 x 32), bf16 in AND out.
// ---------------------------------------------------------------------------
#define PADH 132
__global__ __launch_bounds__(256) void gemm2_kernel(
    const unsigned short* __restrict__ hbf, const float* __restrict__ W2,
    unsigned short* __restrict__ m2bf, int n) {
    __shared__ __align__(16) float sW[HID * OUT_CH];
    __shared__ __align__(16) float sH[HID * PADH];
    const int tid = threadIdx.x;

    {
        const float4* Wv = (const float4*)W2;
        float4* sWv = (float4*)sW;
        for (int i = tid; i < HID * OUT_CH / 4; i += 256) sWv[i] = Wv[i];
    }

    const int R0 = blockIdx.x * 128;
    for (int i = tid; i < 128 * 8; i += 256) {
        int r = i >> 3;
        int q = i & 7;
        int row = R0 + r;
        uint4 v = make_uint4(0u, 0u, 0u, 0u);
        if (row < n)
            v = ((const uint4*)(hbf + (long long)row * HID))[q];
        int k0 = q * 8;
        sH[(k0 + 0) * PADH + r] = bf16_lo(v.x);
        sH[(k0 + 1) * PADH + r] = bf16_hi(v.x);
        sH[(k0 + 2) * PADH + r] = bf16_lo(v.y);
        sH[(k0 + 3) * PADH + r] = bf16_hi(v.y);
        sH[(k0 + 4) * PADH + r] = bf16_lo(v.z);
        sH[(k0 + 5) * PADH + r] = bf16_hi(v.z);
        sH[(k0 + 6) * PADH + r] = bf16_lo(v.w);
        sH[(k0 + 7) * PADH + r] = bf16_hi(v.w);
    }
    __syncthreads();

    const int tx = tid & 7;
    const int ty = tid >> 3;
    float acc[4][4] = {};
    const float* pH = sH + ty * 4;
    const float* pW = sW + tx * 4;
#pragma unroll 8
    for (int k = 0; k < HID; ++k) {
        float4 hv = *(const float4*)(pH + k * PADH);
        float4 wv = *(const float4*)(pW + k * OUT_CH);
        acc[0][0] += hv.x * wv.x; acc[0][1] += hv.x * wv.y;
        acc[0][2] += hv.x * wv.z; acc[0][3] += hv.x * wv.w;
        acc[1][0] += hv.y * wv.x; acc[1][1] += hv.y * wv.y;
        acc[1][2] += hv.y * wv.z; acc[1][3] += hv.y * wv.w;
        acc[2][0] += hv.z * wv.x; acc[2][1] += hv.z * wv.y;
        acc[2][2] += hv.z * wv.z; acc[2][3] += hv.z * wv.w;
        acc[3][0] += hv.w * wv.x; acc[3][1] += hv.w * wv.y;
        acc[3][2] += hv.w * wv.z; acc[3][3] += hv.w * wv.w;
    }

#pragma unroll
    for (int i = 0; i < 4; ++i) {
        int row = R0 + ty * 4 + i;
        if (row < n) {
            ushort4 o;
            o.x = f32_to_bf16(acc[i][0]);
            o.y = f32_to_bf16(acc[i][1]);
            o.z = f32_to_bf16(acc[i][2]);
            o.w = f32_to_bf16(acc[i][3]);
            *(ushort4*)(m2bf + (long long)row * OUT_CH + tx * 4) = o;
        }
    }
}

// ---------------------------------------------------------------------------
// Gather layer 1 (v5 = v4 + register headroom): HALF-WAVE = one node;
// lane-in-half l owns channels 2l,2l+1. __launch_bounds__(256, 4) caps the
// allocator at ~128 VGPR (4 waves/SIMD min) so the 16-deep e[]/v[] tiers
// actually stay in flight (round-7 compiled to 32 VGPR -> ~4-deep effective
// MLP; every gather variant since r4 hit the same ~42us wall because of it).
// ---------------------------------------------------------------------------
__global__ __launch_bounds__(256, 4) void gather64_kernel(
    const int* __restrict__ row_off, const int* __restrict__ counts,
    const int2* __restrict__ ew, const float* __restrict__ dinv,
    const unsigned short* __restrict__ m1bf, const float* __restrict__ b1,
    unsigned short* __restrict__ hbf, int n) {
    const int node = blockIdx.x * 8 + (threadIdx.x >> 5);
    const int l    = threadIdx.x & 31;   // channel pair: ch 2l, 2l+1
    if (node >= n) return;
    const int start = row_off[node];
    const int cnt   = counts[node];

    float a0 = 0.f, a1 = 0.f;
    int j = 0;
    for (; j + 15 < cnt; j += 16) {
        int2 e[16];
#pragma unroll
        for (int u = 0; u < 16; ++u) e[u] = ew[start + j + u];
        unsigned v[16];
#pragma unroll
        for (int u = 0; u < 16; ++u)
            v[u] = *(const unsigned*)(m1bf + (unsigned)(e[u].x * HID) + l * 2);
#pragma unroll
        for (int u = 0; u < 16; ++u) {
            float w = __int_as_float(e[u].y);
            a0 += bf16_lo(v[u]) * w;
            a1 += bf16_hi(v[u]) * w;
        }
    }
    for (; j + 7 < cnt; j += 8) {
        int2 e[8];
#pragma unroll
        for (int u = 0; u < 8; ++u) e[u] = ew[start + j + u];
        unsigned v[8];
#pragma unroll
        for (int u = 0; u < 8; ++u)
            v[u] = *(const unsigned*)(m1bf + (unsigned)(e[u].x * HID) + l * 2);
#pragma unroll
        for (int u = 0; u < 8; ++u) {
            float w = __int_as_float(e[u].y);
            a0 += bf16_lo(v[u]) * w;
            a1 += bf16_hi(v[u]) * w;
        }
    }
    for (; j + 3 < cnt; j += 4) {
        int2 e[4];
#pragma unroll
        for (int u = 0; u < 4; ++u) e[u] = ew[start + j + u];
        unsigned v[4];
#pragma unroll
        for (int u = 0; u < 4; ++u)
            v[u] = *(const unsigned*)(m1bf + (unsigned)(e[u].x * HID) + l * 2);
#pragma unroll
        for (int u = 0; u < 4; ++u) {
            float w = __int_as_float(e[u].y);
            a0 += bf16_lo(v[u]) * w;
            a1 += bf16_hi(v[u]) * w;
        }
    }
    for (; j < cnt; ++j) {
        int2 e = ew[start + j];
        unsigned v = *(const unsigned*)(m1bf + (unsigned)(e.x * HID) + l * 2);
        float w = __int_as_float(e.y);
        a0 += bf16_lo(v) * w;
        a1 += bf16_hi(v) * w;
    }

    float dd = dinv[node];
    float ss = dd * dd;
    unsigned sv = *(const unsigned*)(m1bf + (unsigned)(node * HID) + l * 2);
    ushort2 o;
    o.x = f32_to_bf16(fmaxf(a0 + bf16_lo(sv) * ss + b1[l * 2],     0.f));
    o.y = f32_to_bf16(fmaxf(a1 + bf16_hi(sv) * ss + b1[l * 2 + 1], 0.f));
    *(ushort2*)(hbf + (unsigned)(node * HID) + l * 2) = o;
}

// ---------------------------------------------------------------------------
// Gather layer 2 (v5 = v4 + register headroom, same rationale as gather64).
// ---------------------------------------------------------------------------
__global__ __launch_bounds__(256, 4) void gather32_kernel(
    const int* __restrict__ row_off, const int* __restrict__ counts,
    const int2* __restrict__ ew, const float* __restrict__ dinv,
    const unsigned short* __restrict__ m2bf, const float* __restrict__ b2,
    float* __restrict__ out, int n) {
    const int node = blockIdx.x * 8 + (threadIdx.x >> 5);
    const int l    = threadIdx.x & 31;   // channel
    if (node >= n) return;
    const int start = row_off[node];
    const int cnt   = counts[node];

    float acc = 0.f;
    int j = 0;
    for (; j + 15 < cnt; j += 16) {
        int2 e[16];
#pragma unroll
        for (int u = 0; u < 16; ++u) e[u] = ew[start + j + u];
        unsigned short v[16];
#pragma unroll
        for (int u = 0; u < 16; ++u)
            v[u] = m2bf[(unsigned)(e[u].x * OUT_CH) + l];
#pragma unroll
        for (int u = 0; u < 16; ++u)
            acc += bf16_to_f32(v[u]) * __int_as_float(e[u].y);
    }
    for (; j + 7 < cnt; j += 8) {
        int2 e[8];
#pragma unroll
        for (int u = 0; u < 8; ++u) e[u] = ew[start + j + u];
        unsigned short v[8];
#pragma unroll
        for (int u = 0; u < 8; ++u)
            v[u] = m2bf[(unsigned)(e[u].x * OUT_CH) + l];
#pragma unroll
        for (int u = 0; u < 8; ++u)
            acc += bf16_to_f32(v[u]) * __int_as_float(e[u].y);
    }
    for (; j + 3 < cnt; j += 4) {
        int2 e[4];
#pragma unroll
        for (int u = 0; u < 4; ++u) e[u] = ew[start + j + u];
        unsigned short v[4];
#pragma unroll
        for (int u = 0; u < 4; ++u)
            v[u] = m2bf[(unsigned)(e[u].x * OUT_CH) + l];
#pragma unroll
        for (int u = 0; u < 4; ++u)
            acc += bf16_to_f32(v[u]) * __int_as_float(e[u].y);
    }
    for (; j < cnt; ++j) {
        int2 e = ew[start + j];
        acc += bf16_to_f32(m2bf[(unsigned)(e.x * OUT_CH) + l]) * __int_as_float(e.y);
    }

    float dd = dinv[node];
    float self = bf16_to_f32(m2bf[(unsigned)(node * OUT_CH) + l]);
    out[(unsigned)(node * OUT_CH) + l] = acc + self * dd * dd + b2[l];
}

// ---------------------------------------------------------------------------
// Launch
// ---------------------------------------------------------------------------
extern "C" void kernel_launch(void* const* d_in, const int* in_sizes, int n_in,
                              void* d_out, int out_size, void* d_ws, size_t ws_size,
                              hipStream_t stream) {
    const float* x     = (const float*)d_in[0];
    const void*  edges = d_in[1];
    const float* W1    = (const float*)d_in[2];
    const float* b1    = (const float*)d_in[3];
    const float* W2    = (const float*)d_in[4];
    const float* b2    = (const float*)d_in[5];
    float* out = (float*)d_out;

    const int n = in_sizes[0] / IN_CH;              // 100000
    const long long E = (long long)in_sizes[1] / 2; // 1600000
    const int nb = (n + 255) / 256;                 // 391 buckets

    // Workspace layout (floats):
    // dinv[n] | m1bf: n*HID ushort (also m2bf after gather64) |
    // agg region n*HID floats: entries (binA/binB) then hbf (bf16 h) |
    // counts[n] | row_off[n] | bucket_cur[512] | ew[nb*CAP] int2
    float* ws         = (float*)d_ws;
    float* dinv       = ws;
    unsigned short* m1bf = (unsigned short*)(ws + n);
    unsigned short* m2bf = m1bf;                      // reused after gather64
    float* agg        = ws + n + (long long)n * HID / 2;
    unsigned int* entries = (unsigned int*)agg;       // dead before gather64 writes hbf
    unsigned short* hbf   = (unsigned short*)agg;     // bf16 h, 12.8 MB
    int*   counts     = (int*)(agg + (long long)n * HID);
    int*   row_off    = counts + n;
    int*   bucket_cur = row_off + n;
    int2*  ew         = (int2*)(bucket_cur + NB_MAX); // 8 B aligned

    hipMemsetAsync(bucket_cur, 0, NB_MAX * sizeof(int), stream);

    binA_kernel<<<256, 256, 0, stream>>>(edges, E, bucket_cur, entries, nb);
    binB1_kernel<<<nb, 256, 0, stream>>>(entries, bucket_cur, counts, row_off, dinv, n);
    binB2_kernel<<<nb, 256, 0, stream>>>(entries, bucket_cur, row_off, dinv, ew, n);

    // Layer 1
    gemm1_kernel<<<(n + 63) / 64, 256, 0, stream>>>(x, W1, m1bf, n);
    gather64_kernel<<<(n + 7) / 8, 256, 0, stream>>>(
        row_off, counts, ew, dinv, m1bf, b1, hbf, n);

    // Layer 2
    gemm2_kernel<<<(n + 127) / 128, 256, 0, stream>>>(hbf, W2, m2bf, n);
    gather32_kernel<<<(n + 7) / 8, 256, 0, stream>>>(
        row_off, counts, ew, dinv, m2bf, b2, out, n);
}

// Round 9
// 244.732 us; speedup vs baseline: 1.0539x; 1.0539x over previous
//
#include <hip/hip_runtime.h>

#define IN_CH 128
#define HID 64
#define OUT_CH 32
#define BUCKET_CAP 6144   // mean 4096, sigma ~64 for this E/N; overflow-guarded
#define NB_MAX 512

typedef _Float16 f16x8 __attribute__((ext_vector_type(8)));
typedef float f32x4 __attribute__((ext_vector_type(4)));

// ---------------------------------------------------------------------------
// bf16 helpers (RNE)
// ---------------------------------------------------------------------------
__device__ __forceinline__ unsigned short f32_to_bf16(float f) {
    union { float f; unsigned int u; } v; v.f = f;
    unsigned int u = v.u;
    u += 0x7FFFu + ((u >> 16) & 1u);
    return (unsigned short)(u >> 16);
}
__device__ __forceinline__ float bf16_to_f32(unsigned short h) {
    union { unsigned int u; float f; } v; v.u = ((unsigned int)h) << 16;
    return v.f;
}
__device__ __forceinline__ float bf16_lo(unsigned int u) {
    union { unsigned int u; float f; } v; v.u = u << 16; return v.f;
}
__device__ __forceinline__ float bf16_hi(unsigned int u) {
    union { unsigned int u; float f; } v; v.u = u & 0xFFFF0000u; return v.f;
}

// ---------------------------------------------------------------------------
// edge_index: int64 in reference; int32 possible from harness.
// ---------------------------------------------------------------------------
__device__ __forceinline__ int load_idx(const void* e, long long i, int is64) {
    if (is64) return ((const int*)e)[2 * i];  // little-endian low word
    return ((const int*)e)[i];
}

// ---------------------------------------------------------------------------
// binA: LDS-binned bucketing of edges by dst>>8 into fixed-capacity buckets.
// entry = (src << 8) | (dst & 255). int64-vs-int32 detection fused here.
// ---------------------------------------------------------------------------
__global__ __launch_bounds__(256) void binA_kernel(
    const void* __restrict__ edges, long long E,
    int* __restrict__ bucket_cur, unsigned int* __restrict__ entries, int nb) {
    __shared__ int hist[NB_MAX];
    __shared__ int cbase[NB_MAX];
    __shared__ int s_is64;
    const int tid = threadIdx.x;

    if (tid < 64) {
        int v = ((const int*)edges)[2 * tid + 1];
        unsigned long long nz = __ballot(v != 0);
        if (tid == 0) s_is64 = (nz == 0ull) ? 1 : 0;
    }
    for (int i = tid; i < nb; i += 256) hist[i] = 0;
    __syncthreads();
    const int is64 = s_is64;

    const long long per = (E + gridDim.x - 1) / gridDim.x;
    const long long lo = blockIdx.x * per;
    const long long hi = (lo + per < E) ? lo + per : E;

    for (long long i = lo + tid; i < hi; i += 256) {
        int dst = load_idx(edges, E + i, is64);
        atomicAdd(&hist[dst >> 8], 1);
    }
    __syncthreads();
    for (int i = tid; i < nb; i += 256) {
        int c = hist[i];
        int base = (c > 0) ? atomicAdd(&bucket_cur[i], c) : 0;
        cbase[i] = base;
        hist[i] = 0;  // reuse as running local offset
    }
    __syncthreads();
    for (long long i = lo + tid; i < hi; i += 256) {
        int src = load_idx(edges, i, is64);
        int dst = load_idx(edges, E + i, is64);
        int b = dst >> 8;
        int rel = cbase[b] + atomicAdd(&hist[b], 1);
        if (rel < BUCKET_CAP)
            entries[(long long)b * BUCKET_CAP + rel] = ((unsigned)src << 8) | (unsigned)(dst & 255);
    }
}

// ---------------------------------------------------------------------------
// binB1: block per bucket: LDS per-node hist + scan -> counts, row_off, dinv.
// ---------------------------------------------------------------------------
__global__ __launch_bounds__(256) void binB1_kernel(
    const unsigned int* __restrict__ entries, const int* __restrict__ bucket_cur,
    int* __restrict__ counts, int* __restrict__ row_off, float* __restrict__ dinv,
    int n) {
    __shared__ int hist[256];
    __shared__ int scan[256];
    const int b   = blockIdx.x;
    const int tid = threadIdx.x;
    const long long seg = (long long)b * BUCKET_CAP;
    int cnt = bucket_cur[b];
    if (cnt > BUCKET_CAP) cnt = BUCKET_CAP;

    hist[tid] = 0;
    __syncthreads();
    for (int i = tid; i < cnt; i += 256)
        atomicAdd(&hist[entries[seg + i] & 255], 1);
    __syncthreads();

    int v = hist[tid];
    scan[tid] = v;
    __syncthreads();
    for (int off = 1; off < 256; off <<= 1) {
        int t = (tid >= off) ? scan[tid - off] : 0;
        __syncthreads();
        scan[tid] += t;
        __syncthreads();
    }
    int ex = scan[tid] - v;
    int node = (b << 8) + tid;
    if (node < n) {
        counts[node]  = v;
        row_off[node] = (int)seg + ex;
        dinv[node]    = rsqrtf((float)v + 1.0f);  // +1 self-loop
    }
}

// ---------------------------------------------------------------------------
// binB2: block per bucket: node-sort entries into ew[] with the per-edge
// weight w = dinv[src]*dinv[dst] precomputed. ew entry = int2{src, bits(w)}.
// ---------------------------------------------------------------------------
__global__ __launch_bounds__(256) void binB2_kernel(
    const unsigned int* __restrict__ entries, const int* __restrict__ bucket_cur,
    const int* __restrict__ row_off, const float* __restrict__ dinv,
    int2* __restrict__ ew, int n) {
    __shared__ int cur[256];
    __shared__ float ldi[256];
    const int b   = blockIdx.x;
    const int tid = threadIdx.x;
    const long long seg = (long long)b * BUCKET_CAP;
    int cnt = bucket_cur[b];
    if (cnt > BUCKET_CAP) cnt = BUCKET_CAP;

    int node = (b << 8) + tid;
    cur[tid] = (node < n) ? row_off[node] - (int)seg : 0;
    ldi[tid] = (node < n) ? dinv[node] : 0.f;
    __syncthreads();

    for (int i = tid; i < cnt; i += 256) {
        unsigned e = entries[seg + i];
        int d = (int)(e & 255u);
        int s = (int)(e >> 8);
        int r = atomicAdd(&cur[d], 1);
        float w = dinv[s] * ldi[d];
        int2 o; o.x = s; o.y = __float_as_int(w);
        ew[seg + r] = o;
    }
}

// ---------------------------------------------------------------------------
// GEMM1 via MFMA f16 (round-4 proven version): m1 = x @ W1, fp32 accumulate,
// bf16 out. One wave = one 16-row x 64-col tile: 16 mfma. ZERO LDS/barriers.
// ---------------------------------------------------------------------------
__global__ __launch_bounds__(256) void gemm1_kernel(
    const float* __restrict__ x, const float* __restrict__ W1,
    unsigned short* __restrict__ m1bf, int n) {
    const int lane = threadIdx.x & 63;
    const int wid  = threadIdx.x >> 6;
    const int m    = lane & 15;   // A-row / B-col / D-col within tile
    const int g    = lane >> 4;   // k-group (and D row-group)
    const int Rw   = blockIdx.x * 64 + wid * 16;

    // B fragments: wf[c][t][j] = W1[t*32 + g*8 + j][c*16 + m]
    f16x8 wf[4][4];
#pragma unroll
    for (int t = 0; t < 4; ++t) {
        const float* wp = W1 + (t * 32 + g * 8) * HID + m;
#pragma unroll
        for (int c = 0; c < 4; ++c) {
#pragma unroll
            for (int j = 0; j < 8; ++j)
                wf[c][t][j] = (_Float16)wp[j * HID + c * 16];
        }
    }

    int rl = Rw + m;
    if (rl >= n) rl = n - 1;   // clamp loads; stores guarded below
    const float* xr = x + (long long)rl * IN_CH;

    f32x4 acc[4] = {};

#pragma unroll
    for (int t = 0; t < 4; ++t) {
        float4 xa = *(const float4*)(xr + t * 32 + g * 8);
        float4 xb = *(const float4*)(xr + t * 32 + g * 8 + 4);
        f16x8 af;
        af[0] = (_Float16)xa.x; af[1] = (_Float16)xa.y;
        af[2] = (_Float16)xa.z; af[3] = (_Float16)xa.w;
        af[4] = (_Float16)xb.x; af[5] = (_Float16)xb.y;
        af[6] = (_Float16)xb.z; af[7] = (_Float16)xb.w;
#pragma unroll
        for (int c = 0; c < 4; ++c)
            acc[c] = __builtin_amdgcn_mfma_f32_16x16x32_f16(af, wf[c][t], acc[c], 0, 0, 0);
    }

#pragma unroll
    for (int c = 0; c < 4; ++c) {
#pragma unroll
        for (int r = 0; r < 4; ++r) {
            int row = Rw + g * 4 + r;
            if (row < n)
                m1bf[(long long)row * HID + c * 16 + m] = f32_to_bf16(acc[c][r]);
        }
    }
}

// ---------------------------------------------------------------------------
// GEMM2 (register-tiled): m2 = h @ W2 (N x 64 @ 64 x 32), bf16 in AND out.
// ---------------------------------------------------------------------------
#define PADH 132
__global__ __launch_bounds__(256) void gemm2_kernel(
    const unsigned short* __restrict__ hbf, const float* __restrict__ W2,
    unsigned short* __restrict__ m2bf, int n) {
    __shared__ __align__(16) float sW[HID * OUT_CH];
    __shared__ __align__(16) float sH[HID * PADH];
    const int tid = threadIdx.x;

    {
        const float4* Wv = (const float4*)W2;
        float4* sWv = (float4*)sW;
        for (int i = tid; i < HID * OUT_CH / 4; i += 256) sWv[i] = Wv[i];
    }

    const int R0 = blockIdx.x * 128;
    for (int i = tid; i < 128 * 8; i += 256) {
        int r = i >> 3;
        int q = i & 7;
        int row = R0 + r;
        uint4 v = make_uint4(0u, 0u, 0u, 0u);
        if (row < n)
            v = ((const uint4*)(hbf + (long long)row * HID))[q];
        int k0 = q * 8;
        sH[(k0 + 0) * PADH + r] = bf16_lo(v.x);
        sH[(k0 + 1) * PADH + r] = bf16_hi(v.x);
        sH[(k0 + 2) * PADH + r] = bf16_lo(v.y);
        sH[(k0 + 3) * PADH + r] = bf16_hi(v.y);
        sH[(k0 + 4) * PADH + r] = bf16_lo(v.z);
        sH[(k0 + 5) * PADH + r] = bf16_hi(v.z);
        sH[(k0 + 6) * PADH + r] = bf16_lo(v.w);
        sH[(k0 + 7) * PADH + r] = bf16_hi(v.w);
    }
    __syncthreads();

    const int tx = tid & 7;
    const int ty = tid >> 3;
    float acc[4][4] = {};
    const float* pH = sH + ty * 4;
    const float* pW = sW + tx * 4;
#pragma unroll 8
    for (int k = 0; k < HID; ++k) {
        float4 hv = *(const float4*)(pH + k * PADH);
        float4 wv = *(const float4*)(pW + k * OUT_CH);
        acc[0][0] += hv.x * wv.x; acc[0][1] += hv.x * wv.y;
        acc[0][2] += hv.x * wv.z; acc[0][3] += hv.x * wv.w;
        acc[1][0] += hv.y * wv.x; acc[1][1] += hv.y * wv.y;
        acc[1][2] += hv.y * wv.z; acc[1][3] += hv.y * wv.w;
        acc[2][0] += hv.z * wv.x; acc[2][1] += hv.z * wv.y;
        acc[2][2] += hv.z * wv.z; acc[2][3] += hv.z * wv.w;
        acc[3][0] += hv.w * wv.x; acc[3][1] += hv.w * wv.y;
        acc[3][2] += hv.w * wv.z; acc[3][3] += hv.w * wv.w;
    }

#pragma unroll
    for (int i = 0; i < 4; ++i) {
        int row = R0 + ty * 4 + i;
        if (row < n) {
            ushort4 o;
            o.x = f32_to_bf16(acc[i][0]);
            o.y = f32_to_bf16(acc[i][1]);
            o.z = f32_to_bf16(acc[i][2]);
            o.w = f32_to_bf16(acc[i][3]);
            *(ushort4*)(m2bf + (long long)row * OUT_CH + tx * 4) = o;
        }
    }
}

// ---------------------------------------------------------------------------
// Gather layer 1 (v6): QUARTER-WAVE = one node; lane-in-quarter l=0..15 owns
// channels 4l..4l+3 (uint2 = 4 bf16). 4 nodes per wave -> each gather
// instruction touches 4 DISTINCT rows (2x the half-wave v5). The register
// allocator pins effective load depth at ~8 instrs (VGPR 32, r7/r8 evidence,
// launch_bounds can't raise it); lines-in-flight = depth x lines/instr, so
// doubling lines/instr doubles MLP at identical per-lane pressure.
// Tiers 16/8/4/serial; no shfl folds; 128 B contiguous store per node-group.
// ---------------------------------------------------------------------------
__global__ __launch_bounds__(256, 4) void gather64_kernel(
    const int* __restrict__ row_off, const int* __restrict__ counts,
    const int2* __restrict__ ew, const float* __restrict__ dinv,
    const unsigned short* __restrict__ m1bf, const float* __restrict__ b1,
    unsigned short* __restrict__ hbf, int n) {
    const int node = blockIdx.x * 16 + (threadIdx.x >> 4);
    const int l    = threadIdx.x & 15;   // channel quad: ch 4l..4l+3
    if (node >= n) return;
    const int start = row_off[node];
    const int cnt   = counts[node];

    float a0 = 0.f, a1 = 0.f, a2 = 0.f, a3 = 0.f;
    int j = 0;
    for (; j + 15 < cnt; j += 16) {
        int2 e[16];
#pragma unroll
        for (int u = 0; u < 16; ++u) e[u] = ew[start + j + u];
        uint2 v[16];
#pragma unroll
        for (int u = 0; u < 16; ++u)
            v[u] = *(const uint2*)(m1bf + (unsigned)(e[u].x * HID) + l * 4);
#pragma unroll
        for (int u = 0; u < 16; ++u) {
            float w = __int_as_float(e[u].y);
            a0 += bf16_lo(v[u].x) * w; a1 += bf16_hi(v[u].x) * w;
            a2 += bf16_lo(v[u].y) * w; a3 += bf16_hi(v[u].y) * w;
        }
    }
    for (; j + 7 < cnt; j += 8) {
        int2 e[8];
#pragma unroll
        for (int u = 0; u < 8; ++u) e[u] = ew[start + j + u];
        uint2 v[8];
#pragma unroll
        for (int u = 0; u < 8; ++u)
            v[u] = *(const uint2*)(m1bf + (unsigned)(e[u].x * HID) + l * 4);
#pragma unroll
        for (int u = 0; u < 8; ++u) {
            float w = __int_as_float(e[u].y);
            a0 += bf16_lo(v[u].x) * w; a1 += bf16_hi(v[u].x) * w;
            a2 += bf16_lo(v[u].y) * w; a3 += bf16_hi(v[u].y) * w;
        }
    }
    for (; j + 3 < cnt; j += 4) {
        int2 e[4];
#pragma unroll
        for (int u = 0; u < 4; ++u) e[u] = ew[start + j + u];
        uint2 v[4];
#pragma unroll
        for (int u = 0; u < 4; ++u)
            v[u] = *(const uint2*)(m1bf + (unsigned)(e[u].x * HID) + l * 4);
#pragma unroll
        for (int u = 0; u < 4; ++u) {
            float w = __int_as_float(e[u].y);
            a0 += bf16_lo(v[u].x) * w; a1 += bf16_hi(v[u].x) * w;
            a2 += bf16_lo(v[u].y) * w; a3 += bf16_hi(v[u].y) * w;
        }
    }
    for (; j < cnt; ++j) {
        int2 e = ew[start + j];
        uint2 v = *(const uint2*)(m1bf + (unsigned)(e.x * HID) + l * 4);
        float w = __int_as_float(e.y);
        a0 += bf16_lo(v.x) * w; a1 += bf16_hi(v.x) * w;
        a2 += bf16_lo(v.y) * w; a3 += bf16_hi(v.y) * w;
    }

    float dd = dinv[node];
    float ss = dd * dd;
    uint2 sv = *(const uint2*)(m1bf + (unsigned)(node * HID) + l * 4);
    float4 bv = *(const float4*)(b1 + l * 4);
    ushort4 o;
    o.x = f32_to_bf16(fmaxf(a0 + bf16_lo(sv.x) * ss + bv.x, 0.f));
    o.y = f32_to_bf16(fmaxf(a1 + bf16_hi(sv.x) * ss + bv.y, 0.f));
    o.z = f32_to_bf16(fmaxf(a2 + bf16_lo(sv.y) * ss + bv.z, 0.f));
    o.w = f32_to_bf16(fmaxf(a3 + bf16_hi(sv.y) * ss + bv.w, 0.f));
    *(ushort4*)(hbf + (unsigned)(node * HID) + l * 4) = o;
}

// ---------------------------------------------------------------------------
// Gather layer 2 (v6): QUARTER-WAVE = one node; lane-in-quarter l=0..15 owns
// channels 2l,2l+1 (uint = 2 bf16). 4 nodes/wave -> 4 distinct rows per
// gather instruction. Tiers 16/8/4/serial; no folds; float2 store.
// ---------------------------------------------------------------------------
__global__ __launch_bounds__(256, 4) void gather32_kernel(
    const int* __restrict__ row_off, const int* __restrict__ counts,
    const int2* __restrict__ ew, const float* __restrict__ dinv,
    const unsigned short* __restrict__ m2bf, const float* __restrict__ b2,
    float* __restrict__ out, int n) {
    const int node = blockIdx.x * 16 + (threadIdx.x >> 4);
    const int l    = threadIdx.x & 15;   // channel pair: ch 2l, 2l+1
    if (node >= n) return;
    const int start = row_off[node];
    const int cnt   = counts[node];

    float a0 = 0.f, a1 = 0.f;
    int j = 0;
    for (; j + 15 < cnt; j += 16) {
        int2 e[16];
#pragma unroll
        for (int u = 0; u < 16; ++u) e[u] = ew[start + j + u];
        unsigned v[16];
#pragma unroll
        for (int u = 0; u < 16; ++u)
            v[u] = *(const unsigned*)(m2bf + (unsigned)(e[u].x * OUT_CH) + l * 2);
#pragma unroll
        for (int u = 0; u < 16; ++u) {
            float w = __int_as_float(e[u].y);
            a0 += bf16_lo(v[u]) * w;
            a1 += bf16_hi(v[u]) * w;
        }
    }
    for (; j + 7 < cnt; j += 8) {
        int2 e[8];
#pragma unroll
        for (int u = 0; u < 8; ++u) e[u] = ew[start + j + u];
        unsigned v[8];
#pragma unroll
        for (int u = 0; u < 8; ++u)
            v[u] = *(const unsigned*)(m2bf + (unsigned)(e[u].x * OUT_CH) + l * 2);
#pragma unroll
        for (int u = 0; u < 8; ++u) {
            float w = __int_as_float(e[u].y);
            a0 += bf16_lo(v[u]) * w;
            a1 += bf16_hi(v[u]) * w;
        }
    }
    for (; j + 3 < cnt; j += 4) {
        int2 e[4];
#pragma unroll
        for (int u = 0; u < 4; ++u) e[u] = ew[start + j + u];
        unsigned v[4];
#pragma unroll
        for (int u = 0; u < 4; ++u)
            v[u] = *(const unsigned*)(m2bf + (unsigned)(e[u].x * OUT_CH) + l * 2);
#pragma unroll
        for (int u = 0; u < 4; ++u) {
            float w = __int_as_float(e[u].y);
            a0 += bf16_lo(v[u]) * w;
            a1 += bf16_hi(v[u]) * w;
        }
    }
    for (; j < cnt; ++j) {
        int2 e = ew[start + j];
        unsigned v = *(const unsigned*)(m2bf + (unsigned)(e.x * OUT_CH) + l * 2);
        float w = __int_as_float(e.y);
        a0 += bf16_lo(v) * w;
        a1 += bf16_hi(v) * w;
    }

    float dd = dinv[node];
    float ss = dd * dd;
    unsigned sv = *(const unsigned*)(m2bf + (unsigned)(node * OUT_CH) + l * 2);
    float2 o;
    o.x = a0 + bf16_lo(sv) * ss + b2[l * 2];
    o.y = a1 + bf16_hi(sv) * ss + b2[l * 2 + 1];
    *(float2*)(out + (unsigned)(node * OUT_CH) + l * 2) = o;
}

// ---------------------------------------------------------------------------
// Launch
// ---------------------------------------------------------------------------
extern "C" void kernel_launch(void* const* d_in, const int* in_sizes, int n_in,
                              void* d_out, int out_size, void* d_ws, size_t ws_size,
                              hipStream_t stream) {
    const float* x     = (const float*)d_in[0];
    const void*  edges = d_in[1];
    const float* W1    = (const float*)d_in[2];
    const float* b1    = (const float*)d_in[3];
    const float* W2    = (const float*)d_in[4];
    const float* b2    = (const float*)d_in[5];
    float* out = (float*)d_out;

    const int n = in_sizes[0] / IN_CH;              // 100000
    const long long E = (long long)in_sizes[1] / 2; // 1600000
    const int nb = (n + 255) / 256;                 // 391 buckets

    // Workspace layout (floats):
    // dinv[n] | m1bf: n*HID ushort (also m2bf after gather64) |
    // agg region n*HID floats: entries (binA/binB) then hbf (bf16 h) |
    // counts[n] | row_off[n] | bucket_cur[512] | ew[nb*CAP] int2
    float* ws         = (float*)d_ws;
    float* dinv       = ws;
    unsigned short* m1bf = (unsigned short*)(ws + n);
    unsigned short* m2bf = m1bf;                      // reused after gather64
    float* agg        = ws + n + (long long)n * HID / 2;
    unsigned int* entries = (unsigned int*)agg;       // dead before gather64 writes hbf
    unsigned short* hbf   = (unsigned short*)agg;     // bf16 h, 12.8 MB
    int*   counts     = (int*)(agg + (long long)n * HID);
    int*   row_off    = counts + n;
    int*   bucket_cur = row_off + n;
    int2*  ew         = (int2*)(bucket_cur + NB_MAX); // 8 B aligned

    hipMemsetAsync(bucket_cur, 0, NB_MAX * sizeof(int), stream);

    binA_kernel<<<256, 256, 0, stream>>>(edges, E, bucket_cur, entries, nb);
    binB1_kernel<<<nb, 256, 0, stream>>>(entries, bucket_cur, counts, row_off, dinv, n);
    binB2_kernel<<<nb, 256, 0, stream>>>(entries, bucket_cur, row_off, dinv, ew, n);

    // Layer 1
    gemm1_kernel<<<(n + 63) / 64, 256, 0, stream>>>(x, W1, m1bf, n);
    gather64_kernel<<<(n + 15) / 16, 256, 0, stream>>>(
        row_off, counts, ew, dinv, m1bf, b1, hbf, n);

    // Layer 2
    gemm2_kernel<<<(n + 127) / 128, 256, 0, stream>>>(hbf, W2, m2bf, n);
    gather32_kernel<<<(n + 15) / 16, 256, 0, stream>>>(
        row_off, counts, ew, dinv, m2bf, b2, out, n);
}